// Round 1
// baseline (164.425 us; speedup 1.0000x reference)
//
#include <hip/hip_runtime.h>
#include <hip/hip_bf16.h>
#include <stdint.h>

// Problem constants
#define T_TOK 2048
#define H_DIM 1024
#define I_DIM 768
#define E_NUM 16
#define K_TOP 4
#define NSLOT (T_TOK * K_TOP)   // 8192 (token,k) slots
#define PSLOT 10240             // padded slot capacity: 8192 + 16*128 rounded
#define NTILE 80                // PSLOT / 128 M-tiles

typedef short  s16x8 __attribute__((ext_vector_type(8)));
typedef float  f32x4 __attribute__((ext_vector_type(4)));
typedef unsigned short u16x8 __attribute__((ext_vector_type(8)));

__device__ __forceinline__ void gload16(const void* g, void* l) {
  __builtin_amdgcn_global_load_lds(
      (const __attribute__((address_space(1))) uint32_t*)g,
      (__attribute__((address_space(3))) uint32_t*)l, 16, 0, 0);
}

__device__ __forceinline__ unsigned short f2bf(float f) {
  __hip_bfloat16 h = __float2bfloat16(f);
  return *reinterpret_cast<unsigned short*>(&h);
}

// ---------------- fp32 -> bf16 conversion, 8 elems/thread ----------------
__global__ __launch_bounds__(256) void cvt_bf16_kernel(
    const float* __restrict__ in, unsigned short* __restrict__ out, int n8) {
  int i = blockIdx.x * 256 + threadIdx.x;
  if (i >= n8) return;
  const float4* p = (const float4*)in;
  float4 a = p[2 * (size_t)i];
  float4 b = p[2 * (size_t)i + 1];
  u16x8 o;
  o[0] = f2bf(a.x); o[1] = f2bf(a.y); o[2] = f2bf(a.z); o[3] = f2bf(a.w);
  o[4] = f2bf(b.x); o[5] = f2bf(b.y); o[6] = f2bf(b.z); o[7] = f2bf(b.w);
  *(u16x8*)(out + (size_t)i * 8) = o;
}

// ---------------- deterministic routing: stable counting sort ----------------
// One block, 256 threads. Each thread owns 32 contiguous slots.
// Experts padded to 128-multiples; padding slots get token=0, weight=0.
__global__ __launch_bounds__(256) void route_kernel(
    const int* __restrict__ idx, const float* __restrict__ wts,
    int* __restrict__ slot_tok, float* __restrict__ slot_w,
    int* __restrict__ tile_expert) {
  __shared__ int cnt[256][16];
  __shared__ int tot[16];
  __shared__ int pb[17];
  int tid = threadIdx.x;

  for (int e = 0; e < 16; ++e) cnt[tid][e] = 0;
  // no barrier needed: each thread touches only its own row
  const int s0 = tid * 32;
  for (int i = 0; i < 32; ++i) {
    int e = idx[s0 + i] & 15;
    cnt[tid][e]++;
  }
  __syncthreads();
  if (tid < 16) {  // per-expert exclusive prefix over the 256 chunks
    int run = 0;
    for (int c = 0; c < 256; ++c) { int v = cnt[c][tid]; cnt[c][tid] = run; run += v; }
    tot[tid] = run;
  }
  __syncthreads();
  if (tid == 0) {
    int acc = 0;
    for (int e = 0; e < 16; ++e) { pb[e] = acc; acc += (tot[e] + 127) & ~127; }
    pb[16] = acc;
  }
  __syncthreads();
  // zero full padded arrays (padding zones keep token=0 / w=0)
  for (int p = tid; p < PSLOT; p += 256) { slot_tok[p] = 0; slot_w[p] = 0.0f; }
  // tile -> expert map (tiles past pb[16] are dead)
  if (tid < NTILE) {
    int ef = -1;
    for (int e = 0; e < 16; ++e)
      if (tid * 128 >= pb[e] && tid * 128 < pb[e + 1]) ef = e;
    tile_expert[tid] = ef;
  }
  __syncthreads();  // order zero-writes before scatter overwrites
  for (int i = 0; i < 32; ++i) {
    int s = s0 + i;
    int e = idx[s] & 15;
    int pos = pb[e] + cnt[tid][e]++;
    slot_tok[pos] = s >> 2;       // token id
    slot_w[pos]   = wts[s];
  }
}

// ---------------- GEMM1: gu = X_slots @ Wgu^T, fused silu(g)*u -> h bf16 ----
// BM=128 (slots), BN=64 over BOTH gate and up panels, BK=32.
// 256 thr = 4 waves as 2x2; wave tile 64x32 per panel.
__global__ __launch_bounds__(256) void gemm1_kernel(
    const unsigned short* __restrict__ Xbf,       // [2048][1024]
    const unsigned short* __restrict__ Wgu,       // [16][1536][1024]
    const int* __restrict__ slot_tok,             // [PSLOT]
    const int* __restrict__ tile_expert,          // [NTILE]
    unsigned short* __restrict__ hbuf) {          // [PSLOT][768]
  int e = tile_expert[blockIdx.y];
  if (e < 0) return;
  int bx = blockIdx.x;          // 0..11 : 64-wide N tile (gate index space)
  int m0 = blockIdx.y * 128;
  int tid = threadIdx.x;
  int lane = tid & 63, w = tid >> 6;
  int wr = w >> 1, wc = w & 1;

  __shared__ short lds_a[128 * 32];
  __shared__ short lds_bg[64 * 32];
  __shared__ short lds_bu[64 * 32];

  int r  = tid >> 2;            // 0..63 staging row
  int kb = (tid & 3) * 16;      // byte offset in 64B k-row

  int tok0 = slot_tok[m0 + r];
  int tok1 = slot_tok[m0 + 64 + r];

  const char* gA0 = (const char*)Xbf + (size_t)tok0 * (H_DIM * 2) + kb;
  const char* gA1 = (const char*)Xbf + (size_t)tok1 * (H_DIM * 2) + kb;
  const char* gBg = (const char*)(Wgu + ((size_t)e * 1536 + bx * 64 + r) * H_DIM) + kb;
  const char* gBu = (const char*)(Wgu + ((size_t)e * 1536 + 768 + bx * 64 + r) * H_DIM) + kb;

  char* la  = (char*)lds_a  + tid * 16;
  char* lbg = (char*)lds_bg + tid * 16;
  char* lbu = (char*)lds_bu + tid * 16;

  f32x4 accg[4][2] = {};
  f32x4 accu[4][2] = {};

  for (int kt = 0; kt < H_DIM / 32; ++kt) {
    int koff = kt * 64;
    gload16(gA0 + koff, la);
    gload16(gA1 + koff, la + 4096);
    gload16(gBg + koff, lbg);
    gload16(gBu + koff, lbu);
    __syncthreads();  // drains vmcnt (m97 structure)

    s16x8 af[4], bgf[2], buf2[2];
#pragma unroll
    for (int mi = 0; mi < 4; ++mi)
      af[mi] = *(const s16x8*)(lds_a + (wr * 64 + mi * 16 + (lane & 15)) * 32 + (lane >> 4) * 8);
#pragma unroll
    for (int ni = 0; ni < 2; ++ni) {
      int row = wc * 32 + ni * 16 + (lane & 15);
      bgf[ni]  = *(const s16x8*)(lds_bg + row * 32 + (lane >> 4) * 8);
      buf2[ni] = *(const s16x8*)(lds_bu + row * 32 + (lane >> 4) * 8);
    }
#pragma unroll
    for (int mi = 0; mi < 4; ++mi)
#pragma unroll
      for (int ni = 0; ni < 2; ++ni) {
        accg[mi][ni] = __builtin_amdgcn_mfma_f32_16x16x32_bf16(af[mi], bgf[ni],  accg[mi][ni], 0, 0, 0);
        accu[mi][ni] = __builtin_amdgcn_mfma_f32_16x16x32_bf16(af[mi], buf2[ni], accu[mi][ni], 0, 0, 0);
      }
    __syncthreads();
  }

  // epilogue: h = silu(gate) * up  (C layout: col=lane&15, row=(lane>>4)*4+q)
#pragma unroll
  for (int mi = 0; mi < 4; ++mi) {
#pragma unroll
    for (int ni = 0; ni < 2; ++ni) {
      int col = bx * 64 + wc * 32 + ni * 16 + (lane & 15);
#pragma unroll
      for (int q = 0; q < 4; ++q) {
        int m = m0 + wr * 64 + mi * 16 + (lane >> 4) * 4 + q;
        float g = accg[mi][ni][q];
        float u = accu[mi][ni][q];
        float s = g / (1.0f + __expf(-g));
        hbuf[(size_t)m * I_DIM + col] = f2bf(s * u);
      }
    }
  }
}

// ---------------- GEMM2: out_slot = h @ Wd^T, scaled-atomic scatter --------
// BM=128, BN=128, BK=32; 4 waves 2x2, wave tile 64x64.
__global__ __launch_bounds__(256) void gemm2_kernel(
    const unsigned short* __restrict__ hbuf,      // [PSLOT][768]
    const unsigned short* __restrict__ Wd,        // [16][1024][768]
    const int* __restrict__ slot_tok,
    const float* __restrict__ slot_w,
    const int* __restrict__ tile_expert,
    float* __restrict__ out) {                    // [2048][1024]
  int e = tile_expert[blockIdx.y];
  if (e < 0) return;
  int bx = blockIdx.x;          // 0..7 : 128-wide N tile
  int m0 = blockIdx.y * 128;
  int tid = threadIdx.x;
  int lane = tid & 63, w = tid >> 6;
  int wr = w >> 1, wc = w & 1;

  __shared__ short lds_a[128 * 32];
  __shared__ short lds_b[128 * 32];

  int r  = tid >> 2;
  int kb = (tid & 3) * 16;

  const char* gA = (const char*)(hbuf + (size_t)(m0 + r) * I_DIM) + kb;
  const char* gB = (const char*)(Wd + ((size_t)e * 1024 + bx * 128 + r) * I_DIM) + kb;
  const size_t strideA64 = (size_t)64 * I_DIM * 2;  // +64 rows

  char* la = (char*)lds_a + tid * 16;
  char* lb = (char*)lds_b + tid * 16;

  f32x4 acc[4][4] = {};

  for (int kt = 0; kt < I_DIM / 32; ++kt) {
    int koff = kt * 64;
    gload16(gA + koff, la);
    gload16(gA + strideA64 + koff, la + 4096);
    gload16(gB + koff, lb);
    gload16(gB + strideA64 + koff, lb + 4096);
    __syncthreads();

    s16x8 af[4], bf[4];
#pragma unroll
    for (int mi = 0; mi < 4; ++mi)
      af[mi] = *(const s16x8*)(lds_a + (wr * 64 + mi * 16 + (lane & 15)) * 32 + (lane >> 4) * 8);
#pragma unroll
    for (int ni = 0; ni < 4; ++ni)
      bf[ni] = *(const s16x8*)(lds_b + (wc * 64 + ni * 16 + (lane & 15)) * 32 + (lane >> 4) * 8);
#pragma unroll
    for (int mi = 0; mi < 4; ++mi)
#pragma unroll
      for (int ni = 0; ni < 4; ++ni)
        acc[mi][ni] = __builtin_amdgcn_mfma_f32_16x16x32_bf16(af[mi], bf[ni], acc[mi][ni], 0, 0, 0);
    __syncthreads();
  }

  // epilogue: atomicAdd(out[token], acc * w_slot); skip padding (w==0)
#pragma unroll
  for (int mi = 0; mi < 4; ++mi) {
#pragma unroll
    for (int q = 0; q < 4; ++q) {
      int m = m0 + wr * 64 + mi * 16 + (lane >> 4) * 4 + q;
      float wgt = slot_w[m];
      if (wgt != 0.0f) {
        int tok = slot_tok[m];
        float* orow = out + (size_t)tok * H_DIM + bx * 128 + wc * 64 + (lane & 15);
#pragma unroll
        for (int ni = 0; ni < 4; ++ni)
          atomicAdd(orow + ni * 16, acc[mi][ni][q] * wgt);
      }
    }
  }
}

// ---------------- launch ----------------
extern "C" void kernel_launch(void* const* d_in, const int* in_sizes, int n_in,
                              void* d_out, int out_size, void* d_ws, size_t ws_size,
                              hipStream_t stream) {
  const float* hs       = (const float*)d_in[0];   // [2048][1024]
  const int*   topk_idx = (const int*)d_in[1];     // [2048][4]
  const float* topk_w   = (const float*)d_in[2];   // [2048][4]
  const float* w_gu     = (const float*)d_in[3];   // [16][1536][1024]
  const float* w_d      = (const float*)d_in[4];   // [16][1024][768]
  float* out = (float*)d_out;

  char* ws = (char*)d_ws;
  // ws layout (bytes):
  unsigned short* Xbf   = (unsigned short*)(ws);              //  4,194,304
  unsigned short* Wgubf = (unsigned short*)(ws + 4194304);    // 50,331,648
  unsigned short* Wdbf  = (unsigned short*)(ws + 54525952);   // 25,165,824
  unsigned short* hbuf  = (unsigned short*)(ws + 79691776);   // 15,728,640
  int*   slot_tok    = (int*)(ws + 95420416);                 //     40,960
  float* slot_w      = (float*)(ws + 95461376);               //     40,960
  int*   tile_expert = (int*)(ws + 95502336);                 //        320
  // total ~95.5 MB

  hipMemsetAsync(d_out, 0, (size_t)T_TOK * H_DIM * sizeof(float), stream);

  cvt_bf16_kernel<<<1024,  256, 0, stream>>>(hs,   Xbf,   T_TOK * H_DIM / 8);
  cvt_bf16_kernel<<<12288, 256, 0, stream>>>(w_gu, Wgubf, E_NUM * 2 * I_DIM * H_DIM / 8);
  cvt_bf16_kernel<<<6144,  256, 0, stream>>>(w_d,  Wdbf,  E_NUM * H_DIM * I_DIM / 8);

  route_kernel<<<1, 256, 0, stream>>>(topk_idx, topk_w, slot_tok, slot_w, tile_expert);

  gemm1_kernel<<<dim3(12, NTILE), 256, 0, stream>>>(Xbf, Wgubf, slot_tok, tile_expert, hbuf);
  gemm2_kernel<<<dim3(8, NTILE), 256, 0, stream>>>(hbuf, Wdbf, slot_tok, slot_w, tile_expert, out);
}

// Round 2
// 158.916 us; speedup vs baseline: 1.0347x; 1.0347x over previous
//
#include <hip/hip_runtime.h>
#include <hip/hip_bf16.h>
#include <stdint.h>

// Problem constants
#define T_TOK 2048
#define H_DIM 1024
#define I_DIM 768
#define E_NUM 16
#define K_TOP 4
#define NSLOT (T_TOK * K_TOP)   // 8192 (token,k) slots
#define PSLOT 10240             // padded slot capacity
#define NTILE 80                // PSLOT / 128 M-tiles

typedef short  s16x8 __attribute__((ext_vector_type(8)));
typedef float  f32x4 __attribute__((ext_vector_type(4)));
typedef unsigned short u16x8 __attribute__((ext_vector_type(8)));

__device__ __forceinline__ void gload16(const void* g, void* l) {
  __builtin_amdgcn_global_load_lds(
      (const __attribute__((address_space(1))) uint32_t*)g,
      (__attribute__((address_space(3))) uint32_t*)l, 16, 0, 0);
}

__device__ __forceinline__ unsigned short f2bf(float f) {
  __hip_bfloat16 h = __float2bfloat16(f);
  return *reinterpret_cast<unsigned short*>(&h);
}

// ---------------- fp32 -> bf16 conversion, 8 elems/thread ----------------
__global__ __launch_bounds__(256) void cvt_bf16_kernel(
    const float* __restrict__ in, unsigned short* __restrict__ out, int n8) {
  int i = blockIdx.x * 256 + threadIdx.x;
  if (i >= n8) return;
  const float4* p = (const float4*)in;
  float4 a = p[2 * (size_t)i];
  float4 b = p[2 * (size_t)i + 1];
  u16x8 o;
  o[0] = f2bf(a.x); o[1] = f2bf(a.y); o[2] = f2bf(a.z); o[3] = f2bf(a.w);
  o[4] = f2bf(b.x); o[5] = f2bf(b.y); o[6] = f2bf(b.z); o[7] = f2bf(b.w);
  *(u16x8*)(out + (size_t)i * 8) = o;
}

// ---------------- deterministic routing: stable counting sort ----------------
__global__ __launch_bounds__(256) void route_kernel(
    const int* __restrict__ idx, const float* __restrict__ wts,
    int* __restrict__ slot_tok, float* __restrict__ slot_w,
    int* __restrict__ tile_expert) {
  __shared__ int cnt[256][16];
  __shared__ int tot[16];
  __shared__ int pb[17];
  int tid = threadIdx.x;

  for (int e = 0; e < 16; ++e) cnt[tid][e] = 0;
  const int s0 = tid * 32;
  for (int i = 0; i < 32; ++i) {
    int e = idx[s0 + i] & 15;
    cnt[tid][e]++;
  }
  __syncthreads();
  if (tid < 16) {
    int run = 0;
    for (int c = 0; c < 256; ++c) { int v = cnt[c][tid]; cnt[c][tid] = run; run += v; }
    tot[tid] = run;
  }
  __syncthreads();
  if (tid == 0) {
    int acc = 0;
    for (int e = 0; e < 16; ++e) { pb[e] = acc; acc += (tot[e] + 127) & ~127; }
    pb[16] = acc;
  }
  __syncthreads();
  for (int p = tid; p < PSLOT; p += 256) { slot_tok[p] = 0; slot_w[p] = 0.0f; }
  if (tid < NTILE) {
    int ef = -1;
    for (int e = 0; e < 16; ++e)
      if (tid * 128 >= pb[e] && tid * 128 < pb[e + 1]) ef = e;
    tile_expert[tid] = ef;
  }
  __syncthreads();
  for (int i = 0; i < 32; ++i) {
    int s = s0 + i;
    int e = idx[s] & 15;
    int pos = pb[e] + cnt[tid][e]++;
    slot_tok[pos] = s >> 2;
    slot_w[pos]   = wts[s];
  }
}

// LDS XOR-swizzle: physical 16B-slot p of row r holds logical slot p ^ ((r>>1)&3).
// Staging source column pre-applies the same XOR (involution); reads apply it too.
// Per 8 consecutive lanes, ds_read_b128 then covers all 8 distinct 16B windows
// mod 128B -> conflict-free.

// ---------------- GEMM1: gu = X_slots @ Wgu^T, fused silu(g)*u -> h bf16 ----
// BM=128, BN=64 dual-panel (gate+up), BK=32, 2-phase double-buffered LDS.
__global__ __launch_bounds__(256) void gemm1_kernel(
    const unsigned short* __restrict__ Xbf,       // [2048][1024]
    const unsigned short* __restrict__ Wgu,       // [16][1536][1024]
    const int* __restrict__ slot_tok,             // [PSLOT]
    const int* __restrict__ tile_expert,          // [NTILE]
    unsigned short* __restrict__ hbuf) {          // [PSLOT][768]
  int e = tile_expert[blockIdx.y];
  if (e < 0) return;
  int bx = blockIdx.x;
  int m0 = blockIdx.y * 128;
  int tid = threadIdx.x;
  int lane = tid & 63, w = tid >> 6;
  int wr = w >> 1, wc = w & 1;

  // per buffer (shorts): A[0..4095], Bg[4096..6143], Bu[6144..8191]; 2 buffers
  __shared__ short lds[2 * 8192];

  // staging: row = t>>2 (64B rows), phys slot = t&3, source slot pre-swizzled
  int srow = tid >> 2;
  int swzc = ((tid & 3) ^ ((tid >> 3) & 3)) * 16;   // byte col within 64B window

  int tok0 = slot_tok[m0 + srow];
  int tok1 = slot_tok[m0 + 64 + srow];

  const char* gA0 = (const char*)(Xbf + (size_t)tok0 * H_DIM) + swzc;
  const char* gA1 = (const char*)(Xbf + (size_t)tok1 * H_DIM) + swzc;
  const char* gBg = (const char*)(Wgu + ((size_t)e * 1536 + bx * 64 + srow) * H_DIM) + swzc;
  const char* gBu = (const char*)(Wgu + ((size_t)e * 1536 + 768 + bx * 64 + srow) * H_DIM) + swzc;

  char* lbase = (char*)lds;

  // read-side swizzled slot offset (shorts), constant per lane
  int pswz = ((lane >> 4) ^ (((lane & 15) >> 1) & 3)) * 8;

  f32x4 accg[4][2] = {};
  f32x4 accu[4][2] = {};

#define STAGE1(buf, kt) do {                                  \
    int ko_ = (kt) * 64;                                      \
    char* d_ = lbase + (buf) * 16384 + tid * 16;              \
    gload16(gA0 + ko_, d_);                                   \
    gload16(gA1 + ko_, d_ + 4096);                            \
    gload16(gBg + ko_, d_ + 8192);                            \
    gload16(gBu + ko_, d_ + 12288);                           \
  } while (0)

  STAGE1(0, 0);
  int cur = 0;
  for (int kt = 0; kt < 32; ++kt) {
    if (kt < 31) {
      STAGE1(cur ^ 1, kt + 1);
      asm volatile("s_waitcnt vmcnt(4)" ::: "memory");
    } else {
      asm volatile("s_waitcnt vmcnt(0)" ::: "memory");
    }
    __builtin_amdgcn_s_barrier();

    const short* La = lds + cur * 8192;
    s16x8 af[4], bgf[2], buf2[2];
#pragma unroll
    for (int mi = 0; mi < 4; ++mi)
      af[mi] = *(const s16x8*)(La + (wr * 64 + mi * 16 + (lane & 15)) * 32 + pswz);
#pragma unroll
    for (int ni = 0; ni < 2; ++ni) {
      int row = wc * 32 + ni * 16 + (lane & 15);
      bgf[ni]  = *(const s16x8*)(La + 4096 + row * 32 + pswz);
      buf2[ni] = *(const s16x8*)(La + 6144 + row * 32 + pswz);
    }
#pragma unroll
    for (int mi = 0; mi < 4; ++mi)
#pragma unroll
      for (int ni = 0; ni < 2; ++ni) {
        accg[mi][ni] = __builtin_amdgcn_mfma_f32_16x16x32_bf16(af[mi], bgf[ni],  accg[mi][ni], 0, 0, 0);
        accu[mi][ni] = __builtin_amdgcn_mfma_f32_16x16x32_bf16(af[mi], buf2[ni], accu[mi][ni], 0, 0, 0);
      }
    asm volatile("s_waitcnt lgkmcnt(0)" ::: "memory");
    __builtin_amdgcn_s_barrier();
    cur ^= 1;
  }
#undef STAGE1

  // epilogue: h = silu(gate) * up  (C layout: col=lane&15, row=(lane>>4)*4+q)
#pragma unroll
  for (int mi = 0; mi < 4; ++mi) {
#pragma unroll
    for (int ni = 0; ni < 2; ++ni) {
      int col = bx * 64 + wc * 32 + ni * 16 + (lane & 15);
#pragma unroll
      for (int q = 0; q < 4; ++q) {
        int m = m0 + wr * 64 + mi * 16 + (lane >> 4) * 4 + q;
        float g = accg[mi][ni][q];
        float u = accu[mi][ni][q];
        float s = g / (1.0f + __expf(-g));
        hbuf[(size_t)m * I_DIM + col] = f2bf(s * u);
      }
    }
  }
}

// ---------------- GEMM2: out_slot = h @ Wd^T, scaled-atomic scatter --------
// BM=128, BN=128, BK=32, 2-phase double-buffered LDS.
__global__ __launch_bounds__(256) void gemm2_kernel(
    const unsigned short* __restrict__ hbuf,      // [PSLOT][768]
    const unsigned short* __restrict__ Wd,        // [16][1024][768]
    const int* __restrict__ slot_tok,
    const float* __restrict__ slot_w,
    const int* __restrict__ tile_expert,
    float* __restrict__ out) {                    // [2048][1024]
  int e = tile_expert[blockIdx.y];
  if (e < 0) return;
  int bx = blockIdx.x;
  int m0 = blockIdx.y * 128;
  int tid = threadIdx.x;
  int lane = tid & 63, w = tid >> 6;
  int wr = w >> 1, wc = w & 1;

  // per buffer (shorts): A[0..4095], B[4096..8191]; 2 buffers
  __shared__ short lds[2 * 8192];

  int srow = tid >> 2;
  int swzc = ((tid & 3) ^ ((tid >> 3) & 3)) * 16;

  const char* gA0 = (const char*)(hbuf + (size_t)(m0 + srow) * I_DIM) + swzc;
  const char* gA1 = (const char*)(hbuf + (size_t)(m0 + 64 + srow) * I_DIM) + swzc;
  const char* gB0 = (const char*)(Wd + ((size_t)e * 1024 + bx * 128 + srow) * I_DIM) + swzc;
  const char* gB1 = (const char*)(Wd + ((size_t)e * 1024 + bx * 128 + 64 + srow) * I_DIM) + swzc;

  char* lbase = (char*)lds;
  int pswz = ((lane >> 4) ^ (((lane & 15) >> 1) & 3)) * 8;

  f32x4 acc[4][4] = {};

#define STAGE2(buf, kt) do {                                  \
    int ko_ = (kt) * 64;                                      \
    char* d_ = lbase + (buf) * 16384 + tid * 16;              \
    gload16(gA0 + ko_, d_);                                   \
    gload16(gA1 + ko_, d_ + 4096);                            \
    gload16(gB0 + ko_, d_ + 8192);                            \
    gload16(gB1 + ko_, d_ + 12288);                           \
  } while (0)

  STAGE2(0, 0);
  int cur = 0;
  for (int kt = 0; kt < 24; ++kt) {
    if (kt < 23) {
      STAGE2(cur ^ 1, kt + 1);
      asm volatile("s_waitcnt vmcnt(4)" ::: "memory");
    } else {
      asm volatile("s_waitcnt vmcnt(0)" ::: "memory");
    }
    __builtin_amdgcn_s_barrier();

    const short* La = lds + cur * 8192;
    s16x8 af[4], bf[4];
#pragma unroll
    for (int mi = 0; mi < 4; ++mi)
      af[mi] = *(const s16x8*)(La + (wr * 64 + mi * 16 + (lane & 15)) * 32 + pswz);
#pragma unroll
    for (int ni = 0; ni < 4; ++ni)
      bf[ni] = *(const s16x8*)(La + 4096 + (wc * 64 + ni * 16 + (lane & 15)) * 32 + pswz);
#pragma unroll
    for (int mi = 0; mi < 4; ++mi)
#pragma unroll
      for (int ni = 0; ni < 4; ++ni)
        acc[mi][ni] = __builtin_amdgcn_mfma_f32_16x16x32_bf16(af[mi], bf[ni], acc[mi][ni], 0, 0, 0);
    asm volatile("s_waitcnt lgkmcnt(0)" ::: "memory");
    __builtin_amdgcn_s_barrier();
    cur ^= 1;
  }
#undef STAGE2

  // epilogue: atomicAdd(out[token], acc * w_slot); skip padding (w==0)
#pragma unroll
  for (int mi = 0; mi < 4; ++mi) {
#pragma unroll
    for (int q = 0; q < 4; ++q) {
      int m = m0 + wr * 64 + mi * 16 + (lane >> 4) * 4 + q;
      float wgt = slot_w[m];
      if (wgt != 0.0f) {
        int tok = slot_tok[m];
        float* orow = out + (size_t)tok * H_DIM + bx * 128 + wc * 64 + (lane & 15);
#pragma unroll
        for (int ni = 0; ni < 4; ++ni)
          atomicAdd(orow + ni * 16, acc[mi][ni][q] * wgt);
      }
    }
  }
}

// ---------------- launch ----------------
extern "C" void kernel_launch(void* const* d_in, const int* in_sizes, int n_in,
                              void* d_out, int out_size, void* d_ws, size_t ws_size,
                              hipStream_t stream) {
  const float* hs       = (const float*)d_in[0];   // [2048][1024]
  const int*   topk_idx = (const int*)d_in[1];     // [2048][4]
  const float* topk_w   = (const float*)d_in[2];   // [2048][4]
  const float* w_gu     = (const float*)d_in[3];   // [16][1536][1024]
  const float* w_d      = (const float*)d_in[4];   // [16][1024][768]
  float* out = (float*)d_out;

  char* ws = (char*)d_ws;
  unsigned short* Xbf   = (unsigned short*)(ws);              //  4,194,304
  unsigned short* Wgubf = (unsigned short*)(ws + 4194304);    // 50,331,648
  unsigned short* Wdbf  = (unsigned short*)(ws + 54525952);   // 25,165,824
  unsigned short* hbuf  = (unsigned short*)(ws + 79691776);   // 15,728,640
  int*   slot_tok    = (int*)(ws + 95420416);
  float* slot_w      = (float*)(ws + 95461376);
  int*   tile_expert = (int*)(ws + 95502336);

  hipMemsetAsync(d_out, 0, (size_t)T_TOK * H_DIM * sizeof(float), stream);

  cvt_bf16_kernel<<<1024,  256, 0, stream>>>(hs,   Xbf,   T_TOK * H_DIM / 8);
  cvt_bf16_kernel<<<12288, 256, 0, stream>>>(w_gu, Wgubf, E_NUM * 2 * I_DIM * H_DIM / 8);
  cvt_bf16_kernel<<<6144,  256, 0, stream>>>(w_d,  Wdbf,  E_NUM * H_DIM * I_DIM / 8);

  route_kernel<<<1, 256, 0, stream>>>(topk_idx, topk_w, slot_tok, slot_w, tile_expert);

  gemm1_kernel<<<dim3(12, NTILE), 256, 0, stream>>>(Xbf, Wgubf, slot_tok, tile_expert, hbuf);
  gemm2_kernel<<<dim3(8, NTILE), 256, 0, stream>>>(hbuf, Wdbf, slot_tok, slot_w, tile_expert, out);
}

// Round 3
// 145.171 us; speedup vs baseline: 1.1326x; 1.0947x over previous
//
#include <hip/hip_runtime.h>
#include <hip/hip_bf16.h>
#include <stdint.h>

// Problem constants
#define T_TOK 2048
#define H_DIM 1024
#define I_DIM 768
#define E_NUM 16
#define K_TOP 4
#define NSLOT (T_TOK * K_TOP)   // 8192 (token,k) slots
#define PSLOT 10240             // padded slot capacity
#define NTILE 80                // PSLOT / 128 M-tiles

typedef short  s16x8 __attribute__((ext_vector_type(8)));
typedef float  f32x4 __attribute__((ext_vector_type(4)));
typedef unsigned short u16x8 __attribute__((ext_vector_type(8)));

__device__ __forceinline__ void gload16(const void* g, void* l) {
  __builtin_amdgcn_global_load_lds(
      (const __attribute__((address_space(1))) uint32_t*)g,
      (__attribute__((address_space(3))) uint32_t*)l, 16, 0, 0);
}

__device__ __forceinline__ unsigned short f2bf(float f) {
  __hip_bfloat16 h = __float2bfloat16(f);
  return *reinterpret_cast<unsigned short*>(&h);
}

// fp32x16 -> two bf16x8 chunks, written to swizzled 16B slots of LDS row r.
// Layout contract: phys slot p of row r holds logical k-chunk p ^ ((r>>1)&3).
__device__ __forceinline__ void write_b_row(char* bregion, int r, int half,
                                            f32x4 f0, f32x4 f1, f32x4 f2, f32x4 f3) {
  u16x8 c0, c1;
  c0[0]=f2bf(f0[0]); c0[1]=f2bf(f0[1]); c0[2]=f2bf(f0[2]); c0[3]=f2bf(f0[3]);
  c0[4]=f2bf(f1[0]); c0[5]=f2bf(f1[1]); c0[6]=f2bf(f1[2]); c0[7]=f2bf(f1[3]);
  c1[0]=f2bf(f2[0]); c1[1]=f2bf(f2[1]); c1[2]=f2bf(f2[2]); c1[3]=f2bf(f2[3]);
  c1[4]=f2bf(f3[0]); c1[5]=f2bf(f3[1]); c1[6]=f2bf(f3[2]); c1[7]=f2bf(f3[3]);
  int xr = (r >> 1) & 3;
  char* wb = bregion + r * 64;
  *(u16x8*)(wb + (((2*half + 0) ^ xr) * 16)) = c0;
  *(u16x8*)(wb + (((2*half + 1) ^ xr) * 16)) = c1;
}

// ---------------- fp32 -> bf16 conversion (X only), 8 elems/thread ----------
__global__ __launch_bounds__(256) void cvt_bf16_kernel(
    const float* __restrict__ in, unsigned short* __restrict__ out, int n8) {
  int i = blockIdx.x * 256 + threadIdx.x;
  if (i >= n8) return;
  const float4* p = (const float4*)in;
  float4 a = p[2 * (size_t)i];
  float4 b = p[2 * (size_t)i + 1];
  u16x8 o;
  o[0] = f2bf(a.x); o[1] = f2bf(a.y); o[2] = f2bf(a.z); o[3] = f2bf(a.w);
  o[4] = f2bf(b.x); o[5] = f2bf(b.y); o[6] = f2bf(b.z); o[7] = f2bf(b.w);
  *(u16x8*)(out + (size_t)i * 8) = o;
}

// ---------------- deterministic routing: stable counting sort ----------------
__global__ __launch_bounds__(256) void route_kernel(
    const int* __restrict__ idx, const float* __restrict__ wts,
    int* __restrict__ slot_tok, float* __restrict__ slot_w,
    int* __restrict__ slot_of, int* __restrict__ tile_expert) {
  __shared__ int cnt[256][16];
  __shared__ int tot[16];
  __shared__ int pb[17];
  int tid = threadIdx.x;

  for (int e = 0; e < 16; ++e) cnt[tid][e] = 0;
  const int s0 = tid * 32;
  for (int i = 0; i < 32; ++i) {
    int e = idx[s0 + i] & 15;
    cnt[tid][e]++;
  }
  __syncthreads();
  if (tid < 16) {
    int run = 0;
    for (int c = 0; c < 256; ++c) { int v = cnt[c][tid]; cnt[c][tid] = run; run += v; }
    tot[tid] = run;
  }
  __syncthreads();
  if (tid == 0) {
    int acc = 0;
    for (int e = 0; e < 16; ++e) { pb[e] = acc; acc += (tot[e] + 127) & ~127; }
    pb[16] = acc;
  }
  __syncthreads();
  for (int p = tid; p < PSLOT; p += 256) { slot_tok[p] = 0; slot_w[p] = 0.0f; }
  if (tid < NTILE) {
    int ef = -1;
    for (int e = 0; e < 16; ++e)
      if (tid * 128 >= pb[e] && tid * 128 < pb[e + 1]) ef = e;
    tile_expert[tid] = ef;
  }
  __syncthreads();
  for (int i = 0; i < 32; ++i) {
    int s = s0 + i;
    int e = idx[s] & 15;
    int pos = pb[e] + cnt[tid][e]++;
    slot_tok[pos] = s >> 2;
    slot_w[pos]   = wts[s];
    slot_of[s]    = pos;
  }
}

// ---------------- GEMM1: gu = X_slots @ Wgu^T, fused silu(g)*u -> h bf16 ----
// BM=128, BN=64 dual-panel (gate+up), BK=32, dbuf; A via global_load_lds (bf16),
// B reg-staged from fp32 with in-register cvt + swizzled ds_write.
__global__ __launch_bounds__(256) void gemm1_kernel(
    const unsigned short* __restrict__ Xbf,       // [2048][1024] bf16
    const float* __restrict__ Wgu,                // [16][1536][1024] fp32
    const int* __restrict__ slot_tok,
    const int* __restrict__ tile_expert,
    unsigned short* __restrict__ hbuf) {          // [PSLOT][768] bf16
  int e = tile_expert[blockIdx.y];
  if (e < 0) return;
  int bx = blockIdx.x;
  int m0 = blockIdx.y * 128;
  int tid = threadIdx.x;
  int lane = tid & 63, w = tid >> 6;
  int wr = w >> 1, wc = w & 1;

  // per buffer: A 8KB @0, B(g+u combined, 128 rows) 8KB @8192; 2 buffers
  __shared__ short lds[2 * 8192];
  char* buf0 = (char*)lds;
  char* buf1 = buf0 + 16384;

  // ---- A staging (global_load_lds, source pre-swizzled) ----
  int srow = tid >> 2;
  int swzc = ((tid & 3) ^ ((tid >> 3) & 3)) * 16;
  int tok0 = slot_tok[m0 + srow];
  int tok1 = slot_tok[m0 + 64 + srow];
  const char* gA0 = (const char*)(Xbf + (size_t)tok0 * H_DIM) + swzc;
  const char* gA1 = (const char*)(Xbf + (size_t)tok1 * H_DIM) + swzc;

  // ---- B staging (fp32 reg loads): thread -> (row, half) ----
  int brow = tid >> 1;               // 0..127 combined gate|up rows
  int half = tid & 1;                // which 16-float half of the 32-k window
  int prow = (brow < 64) ? (bx * 64 + brow) : (768 + bx * 64 + (brow - 64));
  const float* gB = Wgu + ((size_t)e * 1536 + prow) * H_DIM + half * 16;

  int pswz = ((lane >> 4) ^ (((lane & 15) >> 1) & 3)) * 8;  // read-side slot (shorts)

  f32x4 accg[4][2] = {};
  f32x4 accu[4][2] = {};
  f32x4 ra0, ra1, ra2, ra3, rb0, rb1, rb2, rb3;

#define G1_STAGE(bufp, r0, r1, r2, r3, kt) do {               \
    int ko_ = (kt) * 64;                                      \
    gload16(gA0 + ko_, (bufp) + tid * 16);                    \
    gload16(gA1 + ko_, (bufp) + 4096 + tid * 16);             \
    const f32x4* p_ = (const f32x4*)(gB + (size_t)(kt) * 32); \
    r0 = p_[0]; r1 = p_[1]; r2 = p_[2]; r3 = p_[3];           \
  } while (0)

#define G1_COMPUTE(bufp) do {                                                          \
    const short* La = (const short*)(bufp);                                            \
    s16x8 af[4], bgf[2], buf2[2];                                                      \
    _Pragma("unroll")                                                                  \
    for (int mi = 0; mi < 4; ++mi)                                                     \
      af[mi] = *(const s16x8*)(La + (wr * 64 + mi * 16 + (lane & 15)) * 32 + pswz);    \
    _Pragma("unroll")                                                                  \
    for (int ni = 0; ni < 2; ++ni) {                                                   \
      int row = wc * 32 + ni * 16 + (lane & 15);                                       \
      bgf[ni]  = *(const s16x8*)(La + 4096 + row * 32 + pswz);                         \
      buf2[ni] = *(const s16x8*)(La + 6144 + row * 32 + pswz);                         \
    }                                                                                  \
    _Pragma("unroll")                                                                  \
    for (int mi = 0; mi < 4; ++mi)                                                     \
      _Pragma("unroll")                                                                \
      for (int ni = 0; ni < 2; ++ni) {                                                 \
        accg[mi][ni] = __builtin_amdgcn_mfma_f32_16x16x32_bf16(af[mi], bgf[ni],  accg[mi][ni], 0, 0, 0); \
        accu[mi][ni] = __builtin_amdgcn_mfma_f32_16x16x32_bf16(af[mi], buf2[ni], accu[mi][ni], 0, 0, 0); \
      }                                                                                \
  } while (0)

  G1_STAGE(buf0, ra0, ra1, ra2, ra3, 0);
  for (int kt = 0; kt < 32; kt += 2) {
    // even sub-iter: tile kt in buf0/ra
    G1_STAGE(buf1, rb0, rb1, rb2, rb3, kt + 1);
    asm volatile("s_waitcnt vmcnt(6)" ::: "memory");
    write_b_row(buf0 + 8192, brow, half, ra0, ra1, ra2, ra3);
    asm volatile("s_waitcnt lgkmcnt(0)" ::: "memory");
    __builtin_amdgcn_s_barrier();
    G1_COMPUTE(buf0);
    __builtin_amdgcn_s_barrier();
    // odd sub-iter: tile kt+1 in buf1/rb
    if (kt + 2 < 32) {
      G1_STAGE(buf0, ra0, ra1, ra2, ra3, kt + 2);
      asm volatile("s_waitcnt vmcnt(6)" ::: "memory");
    } else {
      asm volatile("s_waitcnt vmcnt(0)" ::: "memory");
    }
    write_b_row(buf1 + 8192, brow, half, rb0, rb1, rb2, rb3);
    asm volatile("s_waitcnt lgkmcnt(0)" ::: "memory");
    __builtin_amdgcn_s_barrier();
    G1_COMPUTE(buf1);
    __builtin_amdgcn_s_barrier();
  }
#undef G1_STAGE
#undef G1_COMPUTE

  // epilogue: h = silu(gate) * up  (C layout: col=lane&15, row=(lane>>4)*4+q)
#pragma unroll
  for (int mi = 0; mi < 4; ++mi) {
#pragma unroll
    for (int ni = 0; ni < 2; ++ni) {
      int col = bx * 64 + wc * 32 + ni * 16 + (lane & 15);
#pragma unroll
      for (int q = 0; q < 4; ++q) {
        int m = m0 + wr * 64 + mi * 16 + (lane >> 4) * 4 + q;
        float g = accg[mi][ni][q];
        float u = accu[mi][ni][q];
        float s = g / (1.0f + __expf(-g));
        hbuf[(size_t)m * I_DIM + col] = f2bf(s * u);
      }
    }
  }
}

// ---------------- GEMM2: y_slot = (h @ Wd^T) * w_slot, plain stores ---------
// BM=128, BN=128, BK=32, dbuf; A via global_load_lds (bf16 hbuf),
// B reg-staged from fp32 Wd with cvt + swizzled ds_write.
__global__ __launch_bounds__(256) void gemm2_kernel(
    const unsigned short* __restrict__ hbuf,      // [PSLOT][768] bf16
    const float* __restrict__ Wd,                 // [16][1024][768] fp32
    const int* __restrict__ slot_tok,
    const float* __restrict__ slot_w,
    const int* __restrict__ tile_expert,
    float* __restrict__ y) {                      // [PSLOT][1024] fp32 (pre-scaled)
  int e = tile_expert[blockIdx.y];
  if (e < 0) return;
  int bx = blockIdx.x;
  int m0 = blockIdx.y * 128;
  int tid = threadIdx.x;
  int lane = tid & 63, w = tid >> 6;
  int wr = w >> 1, wc = w & 1;

  __shared__ short lds[2 * 8192];
  char* buf0 = (char*)lds;
  char* buf1 = buf0 + 16384;

  int srow = tid >> 2;
  int swzc = ((tid & 3) ^ ((tid >> 3) & 3)) * 16;
  const char* gA0 = (const char*)(hbuf + (size_t)(m0 + srow) * I_DIM) + swzc;
  const char* gA1 = (const char*)(hbuf + (size_t)(m0 + 64 + srow) * I_DIM) + swzc;

  int brow = tid >> 1;
  int half = tid & 1;
  const float* gB = Wd + ((size_t)e * 1024 + bx * 128 + brow) * I_DIM + half * 16;

  int pswz = ((lane >> 4) ^ (((lane & 15) >> 1) & 3)) * 8;

  f32x4 acc[4][4] = {};
  f32x4 ra0, ra1, ra2, ra3, rb0, rb1, rb2, rb3;

#define G2_STAGE(bufp, r0, r1, r2, r3, kt) do {               \
    int ko_ = (kt) * 64;                                      \
    gload16(gA0 + ko_, (bufp) + tid * 16);                    \
    gload16(gA1 + ko_, (bufp) + 4096 + tid * 16);             \
    const f32x4* p_ = (const f32x4*)(gB + (size_t)(kt) * 32); \
    r0 = p_[0]; r1 = p_[1]; r2 = p_[2]; r3 = p_[3];           \
  } while (0)

#define G2_COMPUTE(bufp) do {                                                          \
    const short* La = (const short*)(bufp);                                            \
    s16x8 af[4], bf[4];                                                                \
    _Pragma("unroll")                                                                  \
    for (int mi = 0; mi < 4; ++mi)                                                     \
      af[mi] = *(const s16x8*)(La + (wr * 64 + mi * 16 + (lane & 15)) * 32 + pswz);    \
    _Pragma("unroll")                                                                  \
    for (int ni = 0; ni < 4; ++ni)                                                     \
      bf[ni] = *(const s16x8*)(La + 4096 + (wc * 64 + ni * 16 + (lane & 15)) * 32 + pswz); \
    _Pragma("unroll")                                                                  \
    for (int mi = 0; mi < 4; ++mi)                                                     \
      _Pragma("unroll")                                                                \
      for (int ni = 0; ni < 4; ++ni)                                                   \
        acc[mi][ni] = __builtin_amdgcn_mfma_f32_16x16x32_bf16(af[mi], bf[ni], acc[mi][ni], 0, 0, 0); \
  } while (0)

  G2_STAGE(buf0, ra0, ra1, ra2, ra3, 0);
  for (int kt = 0; kt < 24; kt += 2) {
    G2_STAGE(buf1, rb0, rb1, rb2, rb3, kt + 1);
    asm volatile("s_waitcnt vmcnt(6)" ::: "memory");
    write_b_row(buf0 + 8192, brow, half, ra0, ra1, ra2, ra3);
    asm volatile("s_waitcnt lgkmcnt(0)" ::: "memory");
    __builtin_amdgcn_s_barrier();
    G2_COMPUTE(buf0);
    __builtin_amdgcn_s_barrier();
    if (kt + 2 < 24) {
      G2_STAGE(buf0, ra0, ra1, ra2, ra3, kt + 2);
      asm volatile("s_waitcnt vmcnt(6)" ::: "memory");
    } else {
      asm volatile("s_waitcnt vmcnt(0)" ::: "memory");
    }
    write_b_row(buf1 + 8192, brow, half, rb0, rb1, rb2, rb3);
    asm volatile("s_waitcnt lgkmcnt(0)" ::: "memory");
    __builtin_amdgcn_s_barrier();
    G2_COMPUTE(buf1);
    __builtin_amdgcn_s_barrier();
  }
#undef G2_STAGE
#undef G2_COMPUTE

  // epilogue: y = acc * w_slot (plain stores; padding rows get 0, never read)
#pragma unroll
  for (int mi = 0; mi < 4; ++mi) {
#pragma unroll
    for (int q = 0; q < 4; ++q) {
      int m = m0 + wr * 64 + mi * 16 + (lane >> 4) * 4 + q;
      float wgt = slot_w[m];
      float* orow = y + (size_t)m * H_DIM + bx * 128 + wc * 64 + (lane & 15);
#pragma unroll
      for (int ni = 0; ni < 4; ++ni)
        orow[ni * 16] = acc[mi][ni][q] * wgt;
    }
  }
}

// ---------------- combine: out[t] = sum_k y[slot_of[t,k]] -------------------
__global__ __launch_bounds__(256) void combine_kernel(
    const float* __restrict__ y, const int* __restrict__ slot_of,
    float* __restrict__ out) {
  int t = blockIdx.x;
  int c = threadIdx.x * 4;
  int s0 = slot_of[t * 4 + 0], s1 = slot_of[t * 4 + 1];
  int s2 = slot_of[t * 4 + 2], s3 = slot_of[t * 4 + 3];
  f32x4 v0 = *(const f32x4*)(y + (size_t)s0 * H_DIM + c);
  f32x4 v1 = *(const f32x4*)(y + (size_t)s1 * H_DIM + c);
  f32x4 v2 = *(const f32x4*)(y + (size_t)s2 * H_DIM + c);
  f32x4 v3 = *(const f32x4*)(y + (size_t)s3 * H_DIM + c);
  f32x4 r = (v0 + v1) + (v2 + v3);
  *(f32x4*)(out + (size_t)t * H_DIM + c) = r;
}

// ---------------- launch ----------------
extern "C" void kernel_launch(void* const* d_in, const int* in_sizes, int n_in,
                              void* d_out, int out_size, void* d_ws, size_t ws_size,
                              hipStream_t stream) {
  const float* hs       = (const float*)d_in[0];   // [2048][1024]
  const int*   topk_idx = (const int*)d_in[1];     // [2048][4]
  const float* topk_w   = (const float*)d_in[2];   // [2048][4]
  const float* w_gu     = (const float*)d_in[3];   // [16][1536][1024]
  const float* w_d      = (const float*)d_in[4];   // [16][1024][768]
  float* out = (float*)d_out;

  char* ws = (char*)d_ws;
  // ws layout (bytes):
  unsigned short* Xbf  = (unsigned short*)(ws);                 //  4,194,304
  unsigned short* hbuf = (unsigned short*)(ws + 4194304);       // 15,728,640
  float*          y    = (float*)(ws + 19922944);               // 41,943,040
  int*   slot_tok    = (int*)(ws + 61865984);                   //     40,960
  float* slot_w      = (float*)(ws + 61906944);                 //     40,960
  int*   slot_of     = (int*)(ws + 61947904);                   //     32,768
  int*   tile_expert = (int*)(ws + 61980672);                   //        320
  // total ~62 MB

  cvt_bf16_kernel<<<1024, 256, 0, stream>>>(hs, Xbf, T_TOK * H_DIM / 8);
  route_kernel<<<1, 256, 0, stream>>>(topk_idx, topk_w, slot_tok, slot_w, slot_of, tile_expert);

  gemm1_kernel<<<dim3(12, NTILE), 256, 0, stream>>>(Xbf, w_gu, slot_tok, tile_expert, hbuf);
  gemm2_kernel<<<dim3(8, NTILE), 256, 0, stream>>>(hbuf, w_d, slot_tok, slot_w, tile_expert, y);
  combine_kernel<<<T_TOK, 256, 0, stream>>>(y, slot_of, out);
}

// Round 5
// 135.406 us; speedup vs baseline: 1.2143x; 1.0721x over previous
//
#include <hip/hip_runtime.h>
#include <hip/hip_bf16.h>
#include <stdint.h>

// Problem constants
#define T_TOK 2048
#define H_DIM 1024
#define I_DIM 768
#define E_NUM 16
#define K_TOP 4
#define NSLOT (T_TOK * K_TOP)   // 8192 (token,k) slots
#define PSLOT 10240             // padded slot capacity
#define NTILE 80                // PSLOT / 128 M-tiles

typedef short  s16x8 __attribute__((ext_vector_type(8)));
typedef float  f32x4 __attribute__((ext_vector_type(4)));
typedef unsigned short u16x8 __attribute__((ext_vector_type(8)));

// compiler memory fence: pins issue order of surrounding memory ops
#define MEMFENCE asm volatile("" ::: "memory")

__device__ __forceinline__ void gload16(const void* g, void* l) {
  __builtin_amdgcn_global_load_lds(
      (const __attribute__((address_space(1))) uint32_t*)g,
      (__attribute__((address_space(3))) uint32_t*)l, 16, 0, 0);
}

__device__ __forceinline__ unsigned short f2bf(float f) {
  __hip_bfloat16 h = __float2bfloat16(f);
  return *reinterpret_cast<unsigned short*>(&h);
}

// fp32x16 -> two bf16x8 chunks, written to swizzled 16B slots of LDS row r.
// Layout contract: phys slot p of row r holds logical slot p ^ ((r>>1)&3).
__device__ __forceinline__ void write_b_row(char* bregion, int r, int half,
                                            f32x4 f0, f32x4 f1, f32x4 f2, f32x4 f3) {
  u16x8 c0, c1;
  c0[0]=f2bf(f0[0]); c0[1]=f2bf(f0[1]); c0[2]=f2bf(f0[2]); c0[3]=f2bf(f0[3]);
  c0[4]=f2bf(f1[0]); c0[5]=f2bf(f1[1]); c0[6]=f2bf(f1[2]); c0[7]=f2bf(f1[3]);
  c1[0]=f2bf(f2[0]); c1[1]=f2bf(f2[1]); c1[2]=f2bf(f2[2]); c1[3]=f2bf(f2[3]);
  c1[4]=f2bf(f3[0]); c1[5]=f2bf(f3[1]); c1[6]=f2bf(f3[2]); c1[7]=f2bf(f3[3]);
  int xr = (r >> 1) & 3;
  char* wb = bregion + r * 64;
  *(u16x8*)(wb + (((2*half + 0) ^ xr) * 16)) = c0;
  *(u16x8*)(wb + (((2*half + 1) ^ xr) * 16)) = c1;
}

// ---------------- fp32 -> bf16 conversion (X only), 8 elems/thread ----------
__global__ __launch_bounds__(256) void cvt_bf16_kernel(
    const float* __restrict__ in, unsigned short* __restrict__ out, int n8) {
  int i = blockIdx.x * 256 + threadIdx.x;
  if (i >= n8) return;
  const float4* p = (const float4*)in;
  float4 a = p[2 * (size_t)i];
  float4 b = p[2 * (size_t)i + 1];
  u16x8 o;
  o[0] = f2bf(a.x); o[1] = f2bf(a.y); o[2] = f2bf(a.z); o[3] = f2bf(a.w);
  o[4] = f2bf(b.x); o[5] = f2bf(b.y); o[6] = f2bf(b.z); o[7] = f2bf(b.w);
  *(u16x8*)(out + (size_t)i * 8) = o;
}

// ---------------- deterministic routing: stable counting sort ----------------
__global__ __launch_bounds__(256) void route_kernel(
    const int* __restrict__ idx, const float* __restrict__ wts,
    int* __restrict__ slot_tok, float* __restrict__ slot_w,
    int* __restrict__ slot_of, int* __restrict__ tile_expert) {
  __shared__ int cnt[256][16];
  __shared__ int tot[16];
  __shared__ int pb[17];
  int tid = threadIdx.x;

  for (int e = 0; e < 16; ++e) cnt[tid][e] = 0;
  const int s0 = tid * 32;
  for (int i = 0; i < 32; ++i) {
    int e = idx[s0 + i] & 15;
    cnt[tid][e]++;
  }
  __syncthreads();
  if (tid < 16) {
    int run = 0;
    for (int c = 0; c < 256; ++c) { int v = cnt[c][tid]; cnt[c][tid] = run; run += v; }
    tot[tid] = run;
  }
  __syncthreads();
  if (tid == 0) {
    int acc = 0;
    for (int e = 0; e < 16; ++e) { pb[e] = acc; acc += (tot[e] + 127) & ~127; }
    pb[16] = acc;
  }
  __syncthreads();
  for (int p = tid; p < PSLOT; p += 256) { slot_tok[p] = 0; slot_w[p] = 0.0f; }
  if (tid < NTILE) {
    int ef = -1;
    for (int e = 0; e < 16; ++e)
      if (tid * 128 >= pb[e] && tid * 128 < pb[e + 1]) ef = e;
    tile_expert[tid] = ef;
  }
  __syncthreads();
  for (int i = 0; i < 32; ++i) {
    int s = s0 + i;
    int e = idx[s] & 15;
    int pos = pb[e] + cnt[tid][e]++;
    slot_tok[pos] = s >> 2;
    slot_w[pos]   = wts[s];
    slot_of[s]    = pos;
  }
}

// Pipeline schedule (both GEMMs), per iter kt (regions fenced so issue order
// is exactly A-then-B; global order ...,A(kt),B(kt+2),A(kt+1),B(kt+3)):
//   A_GLOAD(kt+1) -> Abuf[(kt+1)&1]          (2 vmem; A is L2-warm)
//   B_LOAD(kt+3)  -> regs set[(kt+3)&3]      (4 vmem; load->write dist = 2 iters)
//   vmcnt(10)     retires through A(kt) (incl. older B(kt+1)); 10 stay in flight
//   ds_write B(kt+1) -> Bbuf[(kt+1)&1]; lgkmcnt(0); barrier
//   compute tile kt from buf[kt&1]; barrier
// Prologue: A0, B0, B1, B2 (fenced); vmcnt(8) retires A0+B0; write B0.
// Tail: indices clamped to NT-1 (re-loads real data; writes to dead buffers).

// ---------------- GEMM1: gu = X_slots @ Wgu^T, fused silu(g)*u -> h bf16 ----
__global__ __launch_bounds__(256) void gemm1_kernel(
    const unsigned short* __restrict__ Xbf,       // [2048][1024] bf16
    const float* __restrict__ Wgu,                // [16][1536][1024] fp32
    const int* __restrict__ slot_tok,
    const int* __restrict__ tile_expert,
    unsigned short* __restrict__ hbuf) {          // [PSLOT][768] bf16
  // XCD-chunked remap: 960 blocks, 120 per XCD chunk (bijective, 960%8==0)
  int bid  = blockIdx.y * 12 + blockIdx.x;
  int sbid = (bid & 7) * 120 + (bid >> 3);
  int by   = sbid / 12;
  int bx   = sbid % 12;
  int e = tile_expert[by];
  if (e < 0) return;
  int m0 = by * 128;
  int tid = threadIdx.x;
  int lane = tid & 63, w = tid >> 6;
  int wr = w >> 1, wc = w & 1;

  // per buffer: A 8KB @0, B(g+u combined, 128 rows) 8KB @8192; 2 buffers
  __shared__ short lds[2 * 8192];
  char* buf0 = (char*)lds;
  char* buf1 = buf0 + 16384;

  // ---- A staging (global_load_lds, source pre-swizzled) ----
  int srow = tid >> 2;
  int swzc = ((tid & 3) ^ ((tid >> 3) & 3)) * 16;
  int tok0 = slot_tok[m0 + srow];
  int tok1 = slot_tok[m0 + 64 + srow];
  const char* gA0 = (const char*)(Xbf + (size_t)tok0 * H_DIM) + swzc;
  const char* gA1 = (const char*)(Xbf + (size_t)tok1 * H_DIM) + swzc;

  // ---- B staging (fp32 reg loads): thread -> (row, half) ----
  int brow = tid >> 1;               // 0..127 combined gate|up rows
  int half = tid & 1;
  int prow = (brow < 64) ? (bx * 64 + brow) : (768 + bx * 64 + (brow - 64));
  const float* gB = Wgu + ((size_t)e * 1536 + prow) * H_DIM + half * 16;

  int pswz = ((lane >> 4) ^ (((lane & 15) >> 1) & 3)) * 8;

  f32x4 accg[4][2] = {};
  f32x4 accu[4][2] = {};
  // 4 register sets for B staging (16 f32x4)
  f32x4 s0_0, s0_1, s0_2, s0_3, s1_0, s1_1, s1_2, s1_3;
  f32x4 s2_0, s2_1, s2_2, s2_3, s3_0, s3_1, s3_2, s3_3;

#define NT1 32
#define A_GLOAD1(kt, bufp) do {                               \
    int kk_ = (kt) < NT1 ? (kt) : NT1 - 1;                    \
    int ko_ = kk_ * 64;                                       \
    gload16(gA0 + ko_, (bufp) + tid * 16);                    \
    gload16(gA1 + ko_, (bufp) + 4096 + tid * 16);             \
  } while (0)
#define B_LOAD1(v0, v1, v2, v3, kt) do {                      \
    int kk_ = (kt) < NT1 ? (kt) : NT1 - 1;                    \
    const f32x4* p_ = (const f32x4*)(gB + (size_t)kk_ * 32);  \
    v0 = p_[0]; v1 = p_[1]; v2 = p_[2]; v3 = p_[3];           \
  } while (0)

#define G1_COMPUTE(bufp) do {                                                          \
    const short* La = (const short*)(bufp);                                            \
    s16x8 af[4], bgf[2], buf2[2];                                                      \
    _Pragma("unroll")                                                                  \
    for (int mi = 0; mi < 4; ++mi)                                                     \
      af[mi] = *(const s16x8*)(La + (wr * 64 + mi * 16 + (lane & 15)) * 32 + pswz);    \
    _Pragma("unroll")                                                                  \
    for (int ni = 0; ni < 2; ++ni) {                                                   \
      int row = wc * 32 + ni * 16 + (lane & 15);                                       \
      bgf[ni]  = *(const s16x8*)(La + 4096 + row * 32 + pswz);                         \
      buf2[ni] = *(const s16x8*)(La + 6144 + row * 32 + pswz);                         \
    }                                                                                  \
    _Pragma("unroll")                                                                  \
    for (int mi = 0; mi < 4; ++mi)                                                     \
      _Pragma("unroll")                                                                \
      for (int ni = 0; ni < 2; ++ni) {                                                 \
        accg[mi][ni] = __builtin_amdgcn_mfma_f32_16x16x32_bf16(af[mi], bgf[ni],  accg[mi][ni], 0, 0, 0); \
        accu[mi][ni] = __builtin_amdgcn_mfma_f32_16x16x32_bf16(af[mi], buf2[ni], accu[mi][ni], 0, 0, 0); \
      }                                                                                \
  } while (0)

#define ITER1(kt, wv0, wv1, wv2, wv3, lv0, lv1, lv2, lv3) do {  \
    char* cbuf_ = ((kt) & 1) ? buf1 : buf0;                     \
    char* nbuf_ = ((kt) & 1) ? buf0 : buf1;                     \
    MEMFENCE;                                                   \
    A_GLOAD1((kt) + 1, nbuf_);                                  \
    MEMFENCE;                                                   \
    B_LOAD1(lv0, lv1, lv2, lv3, (kt) + 3);                      \
    asm volatile("s_waitcnt vmcnt(10)" ::: "memory");           \
    write_b_row(nbuf_ + 8192, brow, half, wv0, wv1, wv2, wv3);  \
    asm volatile("s_waitcnt lgkmcnt(0)" ::: "memory");          \
    __builtin_amdgcn_s_barrier();                               \
    MEMFENCE;                                                   \
    G1_COMPUTE(cbuf_);                                          \
    MEMFENCE;                                                   \
    __builtin_amdgcn_s_barrier();                               \
  } while (0)

  // prologue (fenced so issue order is exactly A0,B0,B1,B2)
  A_GLOAD1(0, buf0);
  MEMFENCE;
  B_LOAD1(s0_0, s0_1, s0_2, s0_3, 0);
  MEMFENCE;
  B_LOAD1(s1_0, s1_1, s1_2, s1_3, 1);
  MEMFENCE;
  B_LOAD1(s2_0, s2_1, s2_2, s2_3, 2);
  asm volatile("s_waitcnt vmcnt(8)" ::: "memory");
  write_b_row(buf0 + 8192, brow, half, s0_0, s0_1, s0_2, s0_3);

  for (int kt = 0; kt < NT1; kt += 4) {
    ITER1(kt + 0, s1_0, s1_1, s1_2, s1_3, s3_0, s3_1, s3_2, s3_3);
    ITER1(kt + 1, s2_0, s2_1, s2_2, s2_3, s0_0, s0_1, s0_2, s0_3);
    ITER1(kt + 2, s3_0, s3_1, s3_2, s3_3, s1_0, s1_1, s1_2, s1_3);
    ITER1(kt + 3, s0_0, s0_1, s0_2, s0_3, s2_0, s2_1, s2_2, s2_3);
  }
#undef ITER1
#undef G1_COMPUTE
#undef B_LOAD1
#undef A_GLOAD1

  // epilogue: h = silu(gate) * up  (C layout: col=lane&15, row=(lane>>4)*4+q)
#pragma unroll
  for (int mi = 0; mi < 4; ++mi) {
#pragma unroll
    for (int ni = 0; ni < 2; ++ni) {
      int col = bx * 64 + wc * 32 + ni * 16 + (lane & 15);
#pragma unroll
      for (int q = 0; q < 4; ++q) {
        int m = m0 + wr * 64 + mi * 16 + (lane >> 4) * 4 + q;
        float g = accg[mi][ni][q];
        float u = accu[mi][ni][q];
        float s = g / (1.0f + __expf(-g));
        hbuf[(size_t)m * I_DIM + col] = f2bf(s * u);
      }
    }
  }
}

// ---------------- GEMM2: y_slot = (h @ Wd^T) * w_slot, plain stores ---------
__global__ __launch_bounds__(256) void gemm2_kernel(
    const unsigned short* __restrict__ hbuf,      // [PSLOT][768] bf16
    const float* __restrict__ Wd,                 // [16][1024][768] fp32
    const int* __restrict__ slot_tok,
    const float* __restrict__ slot_w,
    const int* __restrict__ tile_expert,
    float* __restrict__ y) {                      // [PSLOT][1024] fp32
  // XCD-chunked remap: 640 blocks, 80 per XCD chunk
  int bid  = blockIdx.y * 8 + blockIdx.x;
  int sbid = (bid & 7) * 80 + (bid >> 3);
  int by   = sbid >> 3;
  int bx   = sbid & 7;
  int e = tile_expert[by];
  if (e < 0) return;
  int m0 = by * 128;
  int tid = threadIdx.x;
  int lane = tid & 63, w = tid >> 6;
  int wr = w >> 1, wc = w & 1;

  __shared__ short lds[2 * 8192];
  char* buf0 = (char*)lds;
  char* buf1 = buf0 + 16384;

  int srow = tid >> 2;
  int swzc = ((tid & 3) ^ ((tid >> 3) & 3)) * 16;
  const char* gA0 = (const char*)(hbuf + (size_t)(m0 + srow) * I_DIM) + swzc;
  const char* gA1 = (const char*)(hbuf + (size_t)(m0 + 64 + srow) * I_DIM) + swzc;

  int brow = tid >> 1;
  int half = tid & 1;
  const float* gB = Wd + ((size_t)e * 1024 + bx * 128 + brow) * I_DIM + half * 16;

  int pswz = ((lane >> 4) ^ (((lane & 15) >> 1) & 3)) * 8;

  f32x4 acc[4][4] = {};
  f32x4 s0_0, s0_1, s0_2, s0_3, s1_0, s1_1, s1_2, s1_3;
  f32x4 s2_0, s2_1, s2_2, s2_3, s3_0, s3_1, s3_2, s3_3;

#define NT2 24
#define A_GLOAD2(kt, bufp) do {                               \
    int kk_ = (kt) < NT2 ? (kt) : NT2 - 1;                    \
    int ko_ = kk_ * 64;                                       \
    gload16(gA0 + ko_, (bufp) + tid * 16);                    \
    gload16(gA1 + ko_, (bufp) + 4096 + tid * 16);             \
  } while (0)
#define B_LOAD2(v0, v1, v2, v3, kt) do {                      \
    int kk_ = (kt) < NT2 ? (kt) : NT2 - 1;                    \
    const f32x4* p_ = (const f32x4*)(gB + (size_t)kk_ * 32);  \
    v0 = p_[0]; v1 = p_[1]; v2 = p_[2]; v3 = p_[3];           \
  } while (0)

#define G2_COMPUTE(bufp) do {                                                          \
    const short* La = (const short*)(bufp);                                            \
    s16x8 af[4], bf[4];                                                                \
    _Pragma("unroll")                                                                  \
    for (int mi = 0; mi < 4; ++mi)                                                     \
      af[mi] = *(const s16x8*)(La + (wr * 64 + mi * 16 + (lane & 15)) * 32 + pswz);    \
    _Pragma("unroll")                                                                  \
    for (int ni = 0; ni < 4; ++ni)                                                     \
      bf[ni] = *(const s16x8*)(La + 4096 + (wc * 64 + ni * 16 + (lane & 15)) * 32 + pswz); \
    _Pragma("unroll")                                                                  \
    for (int mi = 0; mi < 4; ++mi)                                                     \
      _Pragma("unroll")                                                                \
      for (int ni = 0; ni < 4; ++ni)                                                   \
        acc[mi][ni] = __builtin_amdgcn_mfma_f32_16x16x32_bf16(af[mi], bf[ni], acc[mi][ni], 0, 0, 0); \
  } while (0)

#define ITER2(kt, wv0, wv1, wv2, wv3, lv0, lv1, lv2, lv3) do {  \
    char* cbuf_ = ((kt) & 1) ? buf1 : buf0;                     \
    char* nbuf_ = ((kt) & 1) ? buf0 : buf1;                     \
    MEMFENCE;                                                   \
    A_GLOAD2((kt) + 1, nbuf_);                                  \
    MEMFENCE;                                                   \
    B_LOAD2(lv0, lv1, lv2, lv3, (kt) + 3);                      \
    asm volatile("s_waitcnt vmcnt(10)" ::: "memory");           \
    write_b_row(nbuf_ + 8192, brow, half, wv0, wv1, wv2, wv3);  \
    asm volatile("s_waitcnt lgkmcnt(0)" ::: "memory");          \
    __builtin_amdgcn_s_barrier();                               \
    MEMFENCE;                                                   \
    G2_COMPUTE(cbuf_);                                          \
    MEMFENCE;                                                   \
    __builtin_amdgcn_s_barrier();                               \
  } while (0)

  A_GLOAD2(0, buf0);
  MEMFENCE;
  B_LOAD2(s0_0, s0_1, s0_2, s0_3, 0);
  MEMFENCE;
  B_LOAD2(s1_0, s1_1, s1_2, s1_3, 1);
  MEMFENCE;
  B_LOAD2(s2_0, s2_1, s2_2, s2_3, 2);
  asm volatile("s_waitcnt vmcnt(8)" ::: "memory");
  write_b_row(buf0 + 8192, brow, half, s0_0, s0_1, s0_2, s0_3);

  for (int kt = 0; kt < NT2; kt += 4) {
    ITER2(kt + 0, s1_0, s1_1, s1_2, s1_3, s3_0, s3_1, s3_2, s3_3);
    ITER2(kt + 1, s2_0, s2_1, s2_2, s2_3, s0_0, s0_1, s0_2, s0_3);
    ITER2(kt + 2, s3_0, s3_1, s3_2, s3_3, s1_0, s1_1, s1_2, s1_3);
    ITER2(kt + 3, s0_0, s0_1, s0_2, s0_3, s2_0, s2_1, s2_2, s2_3);
  }
#undef ITER2
#undef G2_COMPUTE
#undef B_LOAD2
#undef A_GLOAD2

  // epilogue: y = acc * w_slot (plain stores; padding rows get 0, never read)
#pragma unroll
  for (int mi = 0; mi < 4; ++mi) {
#pragma unroll
    for (int q = 0; q < 4; ++q) {
      int m = m0 + wr * 64 + mi * 16 + (lane >> 4) * 4 + q;
      float wgt = slot_w[m];
      float* orow = y + (size_t)m * H_DIM + bx * 128 + wc * 64 + (lane & 15);
#pragma unroll
      for (int ni = 0; ni < 4; ++ni)
        orow[ni * 16] = acc[mi][ni][q] * wgt;
    }
  }
}

// ---------------- combine: out[t] = sum_k y[slot_of[t,k]] -------------------
__global__ __launch_bounds__(256) void combine_kernel(
    const float* __restrict__ y, const int* __restrict__ slot_of,
    float* __restrict__ out) {
  int t = blockIdx.x;
  int c = threadIdx.x * 4;
  int s0 = slot_of[t * 4 + 0], s1 = slot_of[t * 4 + 1];
  int s2 = slot_of[t * 4 + 2], s3 = slot_of[t * 4 + 3];
  f32x4 v0 = *(const f32x4*)(y + (size_t)s0 * H_DIM + c);
  f32x4 v1 = *(const f32x4*)(y + (size_t)s1 * H_DIM + c);
  f32x4 v2 = *(const f32x4*)(y + (size_t)s2 * H_DIM + c);
  f32x4 v3 = *(const f32x4*)(y + (size_t)s3 * H_DIM + c);
  f32x4 r = (v0 + v1) + (v2 + v3);
  *(f32x4*)(out + (size_t)t * H_DIM + c) = r;
}

// ---------------- launch ----------------
extern "C" void kernel_launch(void* const* d_in, const int* in_sizes, int n_in,
                              void* d_out, int out_size, void* d_ws, size_t ws_size,
                              hipStream_t stream) {
  const float* hs       = (const float*)d_in[0];   // [2048][1024]
  const int*   topk_idx = (const int*)d_in[1];     // [2048][4]
  const float* topk_w   = (const float*)d_in[2];   // [2048][4]
  const float* w_gu     = (const float*)d_in[3];   // [16][1536][1024]
  const float* w_d      = (const float*)d_in[4];   // [16][1024][768]
  float* out = (float*)d_out;

  char* ws = (char*)d_ws;
  unsigned short* Xbf  = (unsigned short*)(ws);                 //  4,194,304
  unsigned short* hbuf = (unsigned short*)(ws + 4194304);       // 15,728,640
  float*          y    = (float*)(ws + 19922944);               // 41,943,040
  int*   slot_tok    = (int*)(ws + 61865984);
  float* slot_w      = (float*)(ws + 61906944);
  int*   slot_of     = (int*)(ws + 61947904);
  int*   tile_expert = (int*)(ws + 61980672);
  // total ~62 MB

  cvt_bf16_kernel<<<1024, 256, 0, stream>>>(hs, Xbf, T_TOK * H_DIM / 8);
  route_kernel<<<1, 256, 0, stream>>>(topk_idx, topk_w, slot_tok, slot_w, slot_of, tile_expert);

  gemm1_kernel<<<dim3(12, NTILE), 256, 0, stream>>>(Xbf, w_gu, slot_tok, tile_expert, hbuf);
  gemm2_kernel<<<dim3(8, NTILE), 256, 0, stream>>>(hbuf, w_d, slot_tok, slot_w, tile_expert, y);
  combine_kernel<<<T_TOK, 256, 0, stream>>>(y, slot_of, out);
}